// Round 8
// baseline (484.385 us; speedup 1.0000x reference)
//
#include <hip/hip_runtime.h>

typedef unsigned short ushort_t;
typedef unsigned int uint_t;
typedef short short8 __attribute__((ext_vector_type(8)));
typedef float f32x4 __attribute__((ext_vector_type(4)));
typedef float f32x2 __attribute__((ext_vector_type(2)));
typedef uint_t u32x2 __attribute__((ext_vector_type(2)));
typedef _Float16 half2_t __attribute__((ext_vector_type(2)));

__device__ __forceinline__ float sigm(float x) { return 1.f / (1.f + __expf(-x)); }
__device__ __forceinline__ float tanh_s(float x) {
  float e = __expf(2.f * fabsf(x));
  float r = 1.f - 2.f / (e + 1.f);
  return copysignf(r, x);
}
__device__ __forceinline__ float dot2h(half2_t a, half2_t b, float c) {
#if __has_builtin(__builtin_amdgcn_fdot2)
  return __builtin_amdgcn_fdot2(a, b, c, false);
#else
  return c + (float)a.x * (float)b.x + (float)a.y * (float)b.y;
#endif
}
__device__ __forceinline__ uint_t cvtpk_bf16(float a, float b) {
  uint_t r;
  asm("v_cvt_pk_bf16_f32 %0, %1, %2" : "=v"(r) : "v"(a), "v"(b));
  return r;
}
__device__ __forceinline__ short8 ld_cvt8(const float* p) {
  f32x4 v0 = *(const f32x4*)p;
  f32x4 v1 = *(const f32x4*)(p + 4);
  union { short8 s; uint_t u[4]; } r;
  r.u[0] = cvtpk_bf16(v0[0], v0[1]);
  r.u[1] = cvtpk_bf16(v0[2], v0[3]);
  r.u[2] = cvtpk_bf16(v1[0], v1[1]);
  r.u[3] = cvtpk_bf16(v1[2], v1[3]);
  return r.s;
}
__device__ __forceinline__ float f16b2f(uint_t bits) {
  union { ushort_t s; _Float16 h; } v; v.s = (ushort_t)bits; return (float)v.h;
}
__device__ __forceinline__ uint_t f2f16b(float f) {
  union { _Float16 h; ushort_t s; } v; v.h = (_Float16)f; return v.s;
}

#define MFMAB(a, b, c) __builtin_amdgcn_mfma_f32_16x16x32_bf16((a), (b), (c), 0, 0, 0)

// =====================================================================
// Kernel 1 (unchanged, measured ~70 us, PASS): fully-fused gate GEMM.
// G cell (8 bytes, u32x2): lo = {f16 g0+b0, f16 g3+b3}
//                          hi = {f16 g4+b4+gt2, u8 T1, u8 T2}
// =====================================================================
__global__ __launch_bounds__(512) void gemm_g(
    const float* __restrict__ x, const float* __restrict__ td,
    const float* __restrict__ wx, const float* __restrict__ wt,
    const float* __restrict__ bias, u32x2* __restrict__ G,
    int t0, int TC, int ltc, int rpt)
{
  const int tid = threadIdx.x;
  const int wv = tid >> 6, lane = tid & 63;
  const int l15 = lane & 15, lg = lane >> 4;
  const int jj = wv * 16 + l15;

  short8 Bx[5][2], Bt[3][2];
#pragma unroll
  for (int s = 0; s < 5; ++s)
#pragma unroll
    for (int f = 0; f < 2; ++f) {
      const float* wp = wx + (size_t)(f * 32 + lg * 8) * 640 + s * 128 + jj;
      union { short8 v; uint_t u[4]; } r;
#pragma unroll
      for (int q = 0; q < 4; ++q)
        r.u[q] = cvtpk_bf16(wp[(2 * q) * 640], wp[(2 * q + 1) * 640]);
      Bx[s][f] = r.v;
    }
#pragma unroll
  for (int s = 0; s < 3; ++s)
#pragma unroll
    for (int f = 0; f < 2; ++f) {
      const float* wp = wt + (size_t)(f * 32 + lg * 8) * 384 + s * 128 + jj;
      union { short8 v; uint_t u[4]; } r;
#pragma unroll
      for (int q = 0; q < 4; ++q) {
        float w0 = wp[(2 * q) * 384], w1 = wp[(2 * q + 1) * 384];
        if (s == 0) { w0 = fminf(w0, 0.f); w1 = fminf(w1, 0.f); }
        r.u[q] = cvtpk_bf16(w0, w1);
      }
      Bt[s][f] = r.v;
    }

  const float b0f = bias[jj], b1f = bias[128 + jj], b2f = bias[256 + jj];
  const float b3f = bias[384 + jj], b4f = bias[512 + jj];

#pragma unroll 1
  for (int it = 0; it < rpt; ++it) {
    const int m0 = (blockIdx.x * rpt + it) * 16;
    const int m = m0 + l15;
    const int bb = m >> ltc, tt = m & (TC - 1);
    const size_t ro = ((size_t)(bb * 512) + t0 + tt) * 64 + lg * 8;
    short8 xa0 = ld_cvt8(x + ro), xa1 = ld_cvt8(x + ro + 32);
    short8 ta0 = ld_cvt8(td + ro), ta1 = ld_cvt8(td + ro + 32);

    f32x4 g0{}, g1{}, g2{}, g3{}, g4{}, q0{}, q1{}, q2{};
    g0 = MFMAB(xa0, Bx[0][0], g0); g0 = MFMAB(xa1, Bx[0][1], g0);
    g1 = MFMAB(xa0, Bx[1][0], g1); g1 = MFMAB(xa1, Bx[1][1], g1);
    g2 = MFMAB(xa0, Bx[2][0], g2); g2 = MFMAB(xa1, Bx[2][1], g2);
    g3 = MFMAB(xa0, Bx[3][0], g3); g3 = MFMAB(xa1, Bx[3][1], g3);
    g4 = MFMAB(xa0, Bx[4][0], g4); g4 = MFMAB(xa1, Bx[4][1], g4);
    q0 = MFMAB(ta0, Bt[0][0], q0); q0 = MFMAB(ta1, Bt[0][1], q0);
    q1 = MFMAB(ta0, Bt[1][0], q1); q1 = MFMAB(ta1, Bt[1][1], q1);
    q2 = MFMAB(ta0, Bt[2][0], q2); q2 = MFMAB(ta1, Bt[2][1], q2);

#pragma unroll
    for (int r = 0; r < 4; ++r) {
      float v0 = g0[r] + b0f;
      float T1 = sigm(g1[r] + b1f + tanh_s(q0[r]));
      float T2 = sigm(g2[r] + b2f + tanh_s(q1[r]));
      float v3 = g3[r] + b3f;
      float v4 = g4[r] + b4f + q2[r];
      uint_t t1u = (uint_t)(T1 * 255.f + 0.5f);
      uint_t t2u = (uint_t)(T2 * 255.f + 0.5f);
      u32x2 P;
      P[0] = f2f16b(v0) | (f2f16b(v3) << 16);
      P[1] = f2f16b(v4) | (t1u << 16) | (t2u << 24);
      G[(size_t)(m0 + lg * 4 + r) * 128 + jj] = P;
    }
  }
}

// =====================================================================
// Kernel 2: serial scan.  1 block = 1 batch row, 384 threads (6 waves).
// k-split-2 x 2-cols-per-thread: thread (half, p) owns cols 2p, 2p+1 of
// xh and k-range half*64..+63 of Wh (64 half2 in VGPRs).  Per step:
// 8 uniform ds_read_b128 (h) -> 64 dot2 -> one b64 xh write -> barrier
// -> dense gates on threads 0..127 -> barrier.  Raw s_barrier only;
// G prefetched depth-4 in registers.
// =====================================================================
__global__ __launch_bounds__(384) void scan_k(
    const u32x2* __restrict__ G, const float* __restrict__ wh,
    float* __restrict__ out, float* __restrict__ sh, float* __restrict__ sc,
    int t0, int t1, int TC)
{
  __shared__ __attribute__((aligned(16))) _Float16 h_lds[128];
  __shared__ __attribute__((aligned(16))) float xh_lds[768];
  const int tid = threadIdx.x;
  const int b = blockIdx.x;
  const int half = (tid >= 192) ? 1 : 0;
  const int p = tid - half * 192;
  const int c0 = 2 * p;            // this thread's two xh columns: c0, c0+1

  // Wh[half*64 + 2k .. +1][c0..c0+1] as f16 pairs: w2a (col c0), w2b (col c0+1)
  half2_t w2a[32], w2b[32];
  {
    const float* wp = wh + (size_t)(half * 64) * 384 + c0;
#pragma unroll
    for (int k = 0; k < 32; ++k) {
      f32x2 r0 = *(const f32x2*)(wp + (size_t)(2 * k) * 384);
      f32x2 r1 = *(const f32x2*)(wp + (size_t)(2 * k + 1) * 384);
      w2a[k] = half2_t{(_Float16)r0[0], (_Float16)r1[0]};
      w2b[k] = half2_t{(_Float16)r0[1], (_Float16)r1[1]};
    }
  }

  float c_last = 0.f, h0v = 0.f;
  if (tid < 128) {
    if (t0 > 0) { h0v = sh[b * 128 + tid]; c_last = sc[b * 128 + tid]; }
    h_lds[tid] = (_Float16)h0v;
  }
  float h_last = h0v;

  const u32x2* Gp = G + (size_t)b * TC * 128 + (tid & 127);
  float* outp = out + (size_t)b * 65536 + tid;

  u32x2 p0{}, p1{}, p2{}, p3{};
  if (tid < 128) {
    p0 = Gp[0];
    p1 = Gp[128];
    p2 = Gp[256];
    p3 = Gp[384];
  }
  __syncthreads();

#define SCAN_STEP(P, TABS)                                                   \
  {                                                                          \
    u32x2 cur = P;                                                           \
    if (tid < 128) {                                                         \
      int ldr = (TABS) - t0 + 4; if (ldr > TC - 1) ldr = TC - 1;             \
      P = Gp[(size_t)ldr * 128];                                             \
    }                                                                        \
    float a0 = 0.f, a1 = 0.f, a2 = 0.f, a3 = 0.f;                            \
    float e0 = 0.f, e1 = 0.f, e2 = 0.f, e3 = 0.f;                            \
    const short8* hv8 = ((const short8*)h_lds) + half * 8;                   \
    _Pragma("unroll")                                                        \
    for (int kk = 0; kk < 8; ++kk) {                                         \
      union { short8 s; half2_t h[4]; } u; u.s = hv8[kk];                    \
      a0 = dot2h(u.h[0], w2a[kk * 4 + 0], a0);                               \
      e0 = dot2h(u.h[0], w2b[kk * 4 + 0], e0);                               \
      a1 = dot2h(u.h[1], w2a[kk * 4 + 1], a1);                               \
      e1 = dot2h(u.h[1], w2b[kk * 4 + 1], e1);                               \
      a2 = dot2h(u.h[2], w2a[kk * 4 + 2], a2);                               \
      e2 = dot2h(u.h[2], w2b[kk * 4 + 2], e2);                               \
      a3 = dot2h(u.h[3], w2a[kk * 4 + 3], a3);                               \
      e3 = dot2h(u.h[3], w2b[kk * 4 + 3], e3);                               \
    }                                                                        \
    f32x2 s2; s2[0] = (a0 + a1) + (a2 + a3); s2[1] = (e0 + e1) + (e2 + e3);  \
    *(f32x2*)(xh_lds + half * 384 + c0) = s2;                                \
    asm volatile("s_waitcnt lgkmcnt(0)" ::: "memory");                       \
    __builtin_amdgcn_s_barrier();                                            \
    if (tid < 128) {                                                         \
      float xh0 = xh_lds[tid] + xh_lds[tid + 384];                           \
      float xh1 = xh_lds[tid + 128] + xh_lds[tid + 512];                     \
      float xh2 = xh_lds[tid + 256] + xh_lds[tid + 640];                     \
      uint_t lo = cur[0], hi = cur[1];                                       \
      float g0v = f16b2f(lo & 0xffffu), g3v = f16b2f(lo >> 16);              \
      float g4v = f16b2f(hi & 0xffffu);                                      \
      float T1 = (float)((hi >> 16) & 255u) * (1.f / 255.f);                 \
      float T2 = (float)(hi >> 24) * (1.f / 255.f);                          \
      float i_t = sigm(g0v + xh0);                                           \
      float it1 = i_t * T1;                                                  \
      float cwa = tanh_s(g3v + xh1);                                         \
      float ctl = sigm((1.f - it1) * c_last + it1 * cwa);                    \
      float cnw = sigm((1.f - i_t) * c_last + i_t * T2 * cwa);               \
      float o_t = sigm(g4v + xh2);                                           \
      float hn = o_t + tanh_s(ctl);                                          \
      h_lds[tid] = (_Float16)hn;                                             \
      outp[(size_t)(TABS) * 128] = hn;                                       \
      c_last = cnw; h_last = hn;                                             \
    }                                                                        \
    asm volatile("s_waitcnt lgkmcnt(0)" ::: "memory");                       \
    __builtin_amdgcn_s_barrier();                                            \
  }

  for (int t = t0; t < t1; t += 4) {
    SCAN_STEP(p0, t);
    SCAN_STEP(p1, t + 1);
    SCAN_STEP(p2, t + 2);
    SCAN_STEP(p3, t + 3);
  }
#undef SCAN_STEP

  if (tid < 128) {
    if (t1 == 512) {
      out[(size_t)16777216 + b * 128 + tid] = h_last;            // h_f
      out[(size_t)16777216 + 32768 + b * 128 + tid] = c_last;    // c_f
    } else {
      sh[b * 128 + tid] = h_last;
      sc[b * 128 + tid] = c_last;
    }
  }
}

// =====================================================================
extern "C" void kernel_launch(void* const* d_in, const int* in_sizes, int n_in,
                              void* d_out, int out_size, void* d_ws, size_t ws_size,
                              hipStream_t stream) {
  const float* x    = (const float*)d_in[0];
  const float* td   = (const float*)d_in[1];
  const float* wx   = (const float*)d_in[2];
  const float* wh   = (const float*)d_in[3];
  const float* wt   = (const float*)d_in[4];
  const float* bias = (const float*)d_in[5];
  float* out = (float*)d_out;

  // G: 256*TC rows * 128 cols * 8 B (TC=512 -> 134 MB; proven to fit ws)
  int TC = 512;
  while (TC > 16 && (size_t)256 * TC * 128 * 8 + 262144 > ws_size) TC >>= 1;
  int ltc = 0; while ((1 << ltc) < TC) ++ltc;

  u32x2* G = (u32x2*)d_ws;
  float* sh = (float*)((char*)d_ws + (size_t)256 * TC * 128 * 8);
  float* sc = sh + 256 * 128;

  const int rpt = 16;                         // 16-row tiles per gemm block
  const int gblocks = (256 * TC / 16) / rpt;

  for (int t0 = 0; t0 < 512; t0 += TC) {
    gemm_g<<<gblocks, 512, 0, stream>>>(x, td, wx, wt, bias, G, t0, TC, ltc, rpt);
    scan_k<<<256, 384, 0, stream>>>(G, wh, out, sh, sc, t0, t0 + TC, TC);
  }
}